// Round 1
// baseline (256.743 us; speedup 1.0000x reference)
//
#include <hip/hip_runtime.h>
#include <hip/hip_fp16.h>

#define Tt 64
#define Ee 128
#define Aa 10

typedef __attribute__((ext_vector_type(8))) _Float16 half8;
typedef __attribute__((ext_vector_type(8))) short short8;
typedef __attribute__((ext_vector_type(4))) float f32x4;

__device__ __forceinline__ short f2bf(float x) {
    unsigned u = __builtin_bit_cast(unsigned, x);
    u += 0x7fffu + ((u >> 16) & 1u);          // RNE
    return (short)(u >> 16);
}
__device__ __forceinline__ float bf2f(short b) {
    unsigned u = ((unsigned)(unsigned short)b) << 16;
    return __builtin_bit_cast(float, u);
}
__device__ __forceinline__ float fast_rcp(float x) { return __builtin_amdgcn_rcpf(x); }

__device__ __forceinline__ half8 load_h8(const float* p) {
    f32x4 a = *(const f32x4*)p;
    f32x4 b = *(const f32x4*)(p + 4);
    half8 r;
    r[0] = (_Float16)a[0]; r[1] = (_Float16)a[1]; r[2] = (_Float16)a[2]; r[3] = (_Float16)a[3];
    r[4] = (_Float16)b[0]; r[5] = (_Float16)b[1]; r[6] = (_Float16)b[2]; r[7] = (_Float16)b[3];
    return r;
}
__device__ __forceinline__ void load_bf_split(const float* p, short8& hi, short8& lo) {
    f32x4 a = *(const f32x4*)p;
    f32x4 b = *(const f32x4*)(p + 4);
    float v[8] = {a[0], a[1], a[2], a[3], b[0], b[1], b[2], b[3]};
#pragma unroll
    for (int j = 0; j < 8; ++j) {
        short h = f2bf(v[j]);
        hi[j] = h;
        lo[j] = f2bf(v[j] - bf2f(h));
    }
}

#define MFMA_F16(a, b, c)  __builtin_amdgcn_mfma_f32_16x16x32_f16(a, b, c, 0, 0, 0)
#define MFMA_BF16(a, b, c) __builtin_amdgcn_mfma_f32_16x16x32_bf16(a, b, c, 0, 0, 0)

// one WG = 32 rows, 8 waves; wave w owns hidden cols [16w,16w+16): its r-, z-, n- gate tiles.
__global__ __launch_bounds__(512, 2) void gru_fused_kernel(
    const int* __restrict__ utt, const float* __restrict__ emb,
    const float* __restrict__ w_ih, const float* __restrict__ w_hh,
    const float* __restrict__ b_ih, const float* __restrict__ b_hh,
    const float* __restrict__ w_out, const float* __restrict__ b_out,
    float* __restrict__ out) {
    __shared__ __align__(16) char smem[26368];
    char* xbc = smem;                       // [32][128] f16 (swizzled), 8KB
    char* hhb = smem + 8192;                // [32][128] bf16 hi (swizzled), 8KB
    char* hlb = smem + 16384;               // [32][128] bf16 lo (swizzled), 8KB
    int* tokb = (int*)(smem + 24576);       // 32 ints
    float* lg = (float*)(smem + 24832);     // [32][12] logits
    float* outst = (float*)(smem + 8192);   // epilogue: [32][128] f32 (aliases hh/hl)

    const int tid = threadIdx.x;
    const int wv = tid >> 6;
    const int ln = tid & 63;
    const int fn = ln & 15;   // col-in-tile (B n-index / A m-row / C col)
    const int kg = ln >> 4;   // k-group
    const int row0 = blockIdx.x * 32;
    const int gc = wv * 16 + fn;  // hidden col owned by this lane

    // ---- weight fragments in registers ----
    half8 wir[4], wiz[4], win[4];
    short8 whr_h[4], whr_l[4], whz_h[4], whz_l[4], whn_h[4], whn_l[4];
#pragma unroll
    for (int kt = 0; kt < 4; ++kt) {
        int k0 = kt * 32 + kg * 8;
        wir[kt] = load_h8(w_ih + (size_t)gc * Ee + k0);
        wiz[kt] = load_h8(w_ih + (size_t)(128 + gc) * Ee + k0);
        win[kt] = load_h8(w_ih + (size_t)(256 + gc) * Ee + k0);
        load_bf_split(w_hh + (size_t)gc * Ee + k0, whr_h[kt], whr_l[kt]);
        load_bf_split(w_hh + (size_t)(128 + gc) * Ee + k0, whz_h[kt], whz_l[kt]);
        load_bf_split(w_hh + (size_t)(256 + gc) * Ee + k0, whn_h[kt], whn_l[kt]);
    }
    const float bcr = b_ih[gc] + b_hh[gc];
    const float bcz = b_ih[128 + gc] + b_hh[128 + gc];
    const float bin = b_ih[256 + gc];
    const float bhn = b_hh[256 + gc];

    f32x4 hreg[2], oreg[2];
#pragma unroll
    for (int mt = 0; mt < 2; ++mt) {
        hreg[mt] = (f32x4){0.f, 0.f, 0.f, 0.f};
        oreg[mt] = (f32x4){0.f, 0.f, 0.f, 0.f};
    }
    unsigned alive = 0xFFu;  // bit mt*4+i for row mt*16+kg*4+i

#pragma unroll 1
    for (int t = 0; t < Tt; ++t) {
        // ---- stage x_t (emb gather -> f16 LDS) + tokens ----
        {
            int srow = tid >> 4;
            int c8 = (tid & 15) << 3;
            int tok = utt[(row0 + srow) * Tt + t];
            if ((tid & 15) == 0) tokb[srow] = tok;
            half8 hx = load_h8(emb + (size_t)tok * Ee + c8);
            int off = (srow * 256 + c8 * 2) ^ ((srow & 7) << 4);
            *(half8*)(xbc + off) = hx;
        }
        __syncthreads();  // x_t + tokens staged; h_{t-1} visible

        // read this step's death bits (tokb is overwritten next step)
        unsigned newdead = 0;
#pragma unroll
        for (int mt = 0; mt < 2; ++mt)
#pragma unroll
            for (int i = 0; i < 4; ++i)
                if (tokb[mt * 16 + kg * 4 + i] == 0) newdead |= 1u << (mt * 4 + i);

        // ---- MFMA: acc_r/z get x-part + h-part (3-product); i_n,h_n separate ----
        f32x4 ar[2], az[2], ain[2], ahn[2];
#pragma unroll
        for (int mt = 0; mt < 2; ++mt) {
            ar[mt] = (f32x4){0.f, 0.f, 0.f, 0.f};
            az[mt] = (f32x4){0.f, 0.f, 0.f, 0.f};
            ain[mt] = (f32x4){0.f, 0.f, 0.f, 0.f};
            ahn[mt] = (f32x4){0.f, 0.f, 0.f, 0.f};
        }
#pragma unroll
        for (int kt = 0; kt < 4; ++kt) {
#pragma unroll
            for (int mt = 0; mt < 2; ++mt) {
                int r = mt * 16 + fn;
                int off = (r * 256 + (kt * 32 + kg * 8) * 2) ^ ((r & 7) << 4);
                half8 xa = *(const half8*)(xbc + off);
                ar[mt] = MFMA_F16(xa, wir[kt], ar[mt]);
                az[mt] = MFMA_F16(xa, wiz[kt], az[mt]);
                ain[mt] = MFMA_F16(xa, win[kt], ain[mt]);
                if (t > 0) {
                    short8 hh = *(const short8*)(hhb + off);
                    short8 hl = *(const short8*)(hlb + off);
                    ar[mt] = MFMA_BF16(hh, whr_h[kt], ar[mt]);
                    ar[mt] = MFMA_BF16(hh, whr_l[kt], ar[mt]);
                    ar[mt] = MFMA_BF16(hl, whr_h[kt], ar[mt]);
                    az[mt] = MFMA_BF16(hh, whz_h[kt], az[mt]);
                    az[mt] = MFMA_BF16(hh, whz_l[kt], az[mt]);
                    az[mt] = MFMA_BF16(hl, whz_h[kt], az[mt]);
                    ahn[mt] = MFMA_BF16(hh, whn_h[kt], ahn[mt]);
                    ahn[mt] = MFMA_BF16(hh, whn_l[kt], ahn[mt]);
                    ahn[mt] = MFMA_BF16(hl, whn_h[kt], ahn[mt]);
                }
            }
        }
        __syncthreads();  // all LDS reads of x_t / h_{t-1} done

        // ---- gates + h update + output_state (all lane-local) ----
#pragma unroll
        for (int mt = 0; mt < 2; ++mt) {
#pragma unroll
            for (int i = 0; i < 4; ++i) {
                float pr = ar[mt][i] + bcr;
                float pz = az[mt][i] + bcz;
                float rr = fast_rcp(1.f + __expf(-pr));
                float zz = fast_rcp(1.f + __expf(-pz));
                float pn = ain[mt][i] + bin + rr * (ahn[mt][i] + bhn);
                float e2 = __expf(2.f * pn);
                float nn = 1.f - 2.f * fast_rcp(e2 + 1.f);  // tanh(pn)
                float h = (1.f - zz) * nn + zz * hreg[mt][i];
                hreg[mt][i] = h;
                unsigned bit = 1u << (mt * 4 + i);
                if (alive & bit) oreg[mt][i] = h;
                if (t < Tt - 1) {
                    short hi = f2bf(h);
                    short lo = f2bf(h - bf2f(hi));
                    int row = mt * 16 + kg * 4 + i;
                    int off = (row * 256 + gc * 2) ^ ((row & 7) << 4);
                    *(short*)(hhb + off) = hi;
                    *(short*)(hlb + off) = lo;
                }
            }
        }
        alive &= ~newdead;
        // next iteration's staging overwrites xbuf/tokb: safe, reads were before bar2
    }

    // ---- epilogue: logits + softmax ----
#pragma unroll
    for (int mt = 0; mt < 2; ++mt)
#pragma unroll
        for (int i = 0; i < 4; ++i)
            outst[(mt * 16 + kg * 4 + i) * Ee + gc] = oreg[mt][i];
    __syncthreads();

    if (tid < 32 * Aa) {
        int r = tid / Aa, a = tid % Aa;
        const float* wo = w_out + a * Ee;
        const float* os = outst + r * Ee;
        float s = b_out[a];
#pragma unroll
        for (int j = 0; j < Ee; j += 4) {
            f32x4 o = *(const f32x4*)(os + j);
            f32x4 w4 = *(const f32x4*)(wo + j);
            s += o[0] * w4[0] + o[1] * w4[1] + o[2] * w4[2] + o[3] * w4[3];
        }
        lg[r * 12 + a] = s;
    }
    __syncthreads();
    if (tid < 32) {
        float v[Aa];
        float mx = -1e30f;
#pragma unroll
        for (int a = 0; a < Aa; ++a) {
            v[a] = lg[tid * 12 + a];
            mx = fmaxf(mx, v[a]);
        }
        float sum = 0.f;
#pragma unroll
        for (int a = 0; a < Aa; ++a) {
            v[a] = __expf(v[a] - mx);
            sum += v[a];
        }
        float inv = fast_rcp(sum);
#pragma unroll
        for (int a = 0; a < Aa; ++a) out[(size_t)(row0 + tid) * Aa + a] = v[a] * inv;
    }
}

extern "C" void kernel_launch(void* const* d_in, const int* in_sizes, int n_in,
                              void* d_out, int out_size, void* d_ws, size_t ws_size,
                              hipStream_t stream) {
    (void)in_sizes; (void)n_in; (void)d_ws; (void)ws_size; (void)out_size;
    const int* utt = (const int*)d_in[0];
    const float* emb = (const float*)d_in[2];
    const float* wih = (const float*)d_in[3];
    const float* whh = (const float*)d_in[4];
    const float* bih = (const float*)d_in[5];
    const float* bhh = (const float*)d_in[6];
    const float* wout = (const float*)d_in[7];
    const float* bout = (const float*)d_in[8];
    gru_fused_kernel<<<256, 512, 0, stream>>>(utt, emb, wih, whh, bih, bhh, wout, bout,
                                              (float*)d_out);
}

// Round 2
// 201.347 us; speedup vs baseline: 1.2751x; 1.2751x over previous
//
#include <hip/hip_runtime.h>
#include <hip/hip_fp16.h>

#define Tt 64
#define Ee 128
#define Aa 10

typedef __attribute__((ext_vector_type(8))) _Float16 half8;
typedef __attribute__((ext_vector_type(8))) short short8;
typedef __attribute__((ext_vector_type(4))) float f32x4;

__device__ __forceinline__ short f2bf(float x) {
    unsigned u = __builtin_bit_cast(unsigned, x);
    u += 0x7fffu + ((u >> 16) & 1u);          // RNE
    return (short)(u >> 16);
}
__device__ __forceinline__ float bf2f(short b) {
    unsigned u = ((unsigned)(unsigned short)b) << 16;
    return __builtin_bit_cast(float, u);
}
__device__ __forceinline__ float fast_rcp(float x) { return __builtin_amdgcn_rcpf(x); }

__device__ __forceinline__ half8 load_h8(const float* p) {
    f32x4 a = *(const f32x4*)p;
    f32x4 b = *(const f32x4*)(p + 4);
    half8 r;
    r[0] = (_Float16)a[0]; r[1] = (_Float16)a[1]; r[2] = (_Float16)a[2]; r[3] = (_Float16)a[3];
    r[4] = (_Float16)b[0]; r[5] = (_Float16)b[1]; r[6] = (_Float16)b[2]; r[7] = (_Float16)b[3];
    return r;
}
__device__ __forceinline__ void load_bf_split(const float* p, short8& hi, short8& lo) {
    f32x4 a = *(const f32x4*)p;
    f32x4 b = *(const f32x4*)(p + 4);
    float v[8] = {a[0], a[1], a[2], a[3], b[0], b[1], b[2], b[3]};
#pragma unroll
    for (int j = 0; j < 8; ++j) {
        short h = f2bf(v[j]);
        hi[j] = h;
        lo[j] = f2bf(v[j] - bf2f(h));
    }
}

#define MFMA_F16(a, b, c)  __builtin_amdgcn_mfma_f32_16x16x32_f16(a, b, c, 0, 0, 0)
#define MFMA_BF16(a, b, c) __builtin_amdgcn_mfma_f32_16x16x32_bf16(a, b, c, 0, 0, 0)

// LDS layout (bytes):
//   0      tokb   [32][64] int              8192
//   8192   X0     [32][128] f16 swizzled    8192   (epilogue: outst f32 aliases 8192..24576)
//   16384  X1                               8192
//   24576  HH0    [32][128] bf16-hi swz     8192
//   32768  HL0    [32][128] bf16-lo swz     8192
//   40960  HH1                              8192
//   49152  HL1                              8192
//   57344  lg     [32][12] f32              1536
//   58880  tstar  [32] int                   128
#define SM_BYTES 59136

// one WG = 32 rows, 8 waves; wave w owns hidden cols [16w,16w+16): its r-, z-, n- gate tiles.
__global__ __launch_bounds__(512, 2) void gru_fused_kernel(
    const int* __restrict__ utt, const float* __restrict__ emb,
    const float* __restrict__ w_ih, const float* __restrict__ w_hh,
    const float* __restrict__ b_ih, const float* __restrict__ b_hh,
    const float* __restrict__ w_out, const float* __restrict__ b_out,
    float* __restrict__ out) {
    __shared__ __align__(16) char smem[SM_BYTES];
    int* tokb = (int*)smem;
    float* lg = (float*)(smem + 57344);
    int* tstar = (int*)(smem + 58880);
    float* outst = (float*)(smem + 8192);

    const int tid = threadIdx.x;
    const int wv = tid >> 6;
    const int ln = tid & 63;
    const int fn = ln & 15;   // col-in-tile (B n-index / A m-row / C col)
    const int kg = ln >> 4;   // k-group
    const int row0 = blockIdx.x * 32;
    const int gc = wv * 16 + fn;  // hidden col owned by this lane
    const int srow = tid >> 4;          // staging row
    const int c8 = (tid & 15) << 3;     // staging col (8 floats)

    // ---- prologue: init tstar, zero h buffers (h0 = 0 -> MFMAs exact) ----
    if (tid < 32) tstar[tid] = Tt - 1;
    {
        f32x4 z = {0.f, 0.f, 0.f, 0.f};
        *(f32x4*)(smem + 24576 + tid * 32) = z;
        *(f32x4*)(smem + 24576 + tid * 32 + 16) = z;
    }
    __syncthreads();
    // ---- stage all tokens + death-step scan ----
    {
        int4 tv = ((const int4*)(utt + (size_t)row0 * Tt))[tid];
        ((int4*)tokb)[tid] = tv;
        int row = tid >> 4;
        int tq = (tid & 15) << 2;
        if (tv.x == 0) atomicMin(&tstar[row], tq);
        if (tv.y == 0) atomicMin(&tstar[row], tq + 1);
        if (tv.z == 0) atomicMin(&tstar[row], tq + 2);
        if (tv.w == 0) atomicMin(&tstar[row], tq + 3);
    }

    // ---- weight fragments in registers ----
    half8 wir[4], wiz[4], win[4];
    short8 whr_h[4], whr_l[4], whz_h[4], whz_l[4], whn_h[4], whn_l[4];
#pragma unroll
    for (int kt = 0; kt < 4; ++kt) {
        int k0 = kt * 32 + kg * 8;
        wir[kt] = load_h8(w_ih + (size_t)gc * Ee + k0);
        wiz[kt] = load_h8(w_ih + (size_t)(128 + gc) * Ee + k0);
        win[kt] = load_h8(w_ih + (size_t)(256 + gc) * Ee + k0);
        load_bf_split(w_hh + (size_t)gc * Ee + k0, whr_h[kt], whr_l[kt]);
        load_bf_split(w_hh + (size_t)(128 + gc) * Ee + k0, whz_h[kt], whz_l[kt]);
        load_bf_split(w_hh + (size_t)(256 + gc) * Ee + k0, whn_h[kt], whn_l[kt]);
    }
    const float bcr = b_ih[gc] + b_hh[gc];
    const float bcz = b_ih[128 + gc] + b_hh[128 + gc];
    const float bin = b_ih[256 + gc];
    const float bhn = b_hh[256 + gc];
    __syncthreads();

    // death steps for this lane's 8 rows
    int ts[8];
#pragma unroll
    for (int mt = 0; mt < 2; ++mt)
#pragma unroll
        for (int i = 0; i < 4; ++i) ts[mt * 4 + i] = tstar[mt * 16 + kg * 4 + i];

    // ---- stage x_0 ----
    {
        int tok = tokb[srow * Tt];
        const float* p = emb + (size_t)tok * Ee + c8;
        f32x4 a = *(const f32x4*)p;
        f32x4 b = *(const f32x4*)(p + 4);
        half8 hx;
#pragma unroll
        for (int j = 0; j < 4; ++j) { hx[j] = (_Float16)a[j]; hx[4 + j] = (_Float16)b[j]; }
        int off = (srow * 256 + c8 * 2) ^ ((srow & 7) << 4);
        *(half8*)(smem + 8192 + off) = hx;
    }
    __syncthreads();

    f32x4 hreg[2], oreg[2];
#pragma unroll
    for (int mt = 0; mt < 2; ++mt) {
        hreg[mt] = (f32x4){0.f, 0.f, 0.f, 0.f};
        oreg[mt] = (f32x4){0.f, 0.f, 0.f, 0.f};
    }

    int cur = 0;
#pragma unroll 1
    for (int t = 0; t < Tt; ++t) {
        // ---- issue prefetch of x_{t+1} (latency hides under MFMA phase) ----
        f32x4 pa, pb;
        if (t < Tt - 1) {
            int tok = tokb[srow * Tt + t + 1];
            const float* p = emb + (size_t)tok * Ee + c8;
            pa = *(const f32x4*)p;
            pb = *(const f32x4*)(p + 4);
        }

        const char* xb = smem + 8192 + cur * 8192;
        const char* hh_ = smem + 24576 + cur * 16384;
        const char* hl_ = hh_ + 8192;

        // ---- MFMA: acc_r/z get x-part + h-part (3-product); i_n,h_n separate ----
        f32x4 ar[2], az[2], ain[2], ahn[2];
#pragma unroll
        for (int mt = 0; mt < 2; ++mt) {
            ar[mt] = (f32x4){0.f, 0.f, 0.f, 0.f};
            az[mt] = (f32x4){0.f, 0.f, 0.f, 0.f};
            ain[mt] = (f32x4){0.f, 0.f, 0.f, 0.f};
            ahn[mt] = (f32x4){0.f, 0.f, 0.f, 0.f};
        }
#pragma unroll
        for (int kt = 0; kt < 4; ++kt) {
#pragma unroll
            for (int mt = 0; mt < 2; ++mt) {
                int r = mt * 16 + fn;
                int off = (r * 256 + (kt * 32 + kg * 8) * 2) ^ ((r & 7) << 4);
                half8 xa = *(const half8*)(xb + off);
                short8 hh = *(const short8*)(hh_ + off);
                short8 hl = *(const short8*)(hl_ + off);
                ar[mt] = MFMA_F16(xa, wir[kt], ar[mt]);
                az[mt] = MFMA_F16(xa, wiz[kt], az[mt]);
                ain[mt] = MFMA_F16(xa, win[kt], ain[mt]);
                ar[mt] = MFMA_BF16(hh, whr_h[kt], ar[mt]);
                ar[mt] = MFMA_BF16(hh, whr_l[kt], ar[mt]);
                ar[mt] = MFMA_BF16(hl, whr_h[kt], ar[mt]);
                az[mt] = MFMA_BF16(hh, whz_h[kt], az[mt]);
                az[mt] = MFMA_BF16(hh, whz_l[kt], az[mt]);
                az[mt] = MFMA_BF16(hl, whz_h[kt], az[mt]);
                ahn[mt] = MFMA_BF16(hh, whn_h[kt], ahn[mt]);
                ahn[mt] = MFMA_BF16(hh, whn_l[kt], ahn[mt]);
                ahn[mt] = MFMA_BF16(hl, whn_h[kt], ahn[mt]);
            }
        }

        char* hhn = smem + 24576 + (cur ^ 1) * 16384;
        char* hln = hhn + 8192;

        // ---- gates + h update + snapshot (lane-local); write h_t to NEXT buffer ----
#pragma unroll
        for (int mt = 0; mt < 2; ++mt) {
#pragma unroll
            for (int i = 0; i < 4; ++i) {
                float pr = ar[mt][i] + bcr;
                float pz = az[mt][i] + bcz;
                float rr = fast_rcp(1.f + __expf(-pr));
                float zz = fast_rcp(1.f + __expf(-pz));
                float pn = ain[mt][i] + bin + rr * (ahn[mt][i] + bhn);
                float e2 = __expf(2.f * pn);
                float nn = 1.f - 2.f * fast_rcp(e2 + 1.f);  // tanh(pn)
                float h = (1.f - zz) * nn + zz * hreg[mt][i];
                hreg[mt][i] = h;
                if (t == ts[mt * 4 + i]) oreg[mt][i] = h;
                if (t < Tt - 1) {
                    short hi = f2bf(h);
                    short lo = f2bf(h - bf2f(hi));
                    int row = mt * 16 + kg * 4 + i;
                    int off = (row * 256 + gc * 2) ^ ((row & 7) << 4);
                    *(short*)(hhn + off) = hi;
                    *(short*)(hln + off) = lo;
                }
            }
        }
        // ---- commit prefetched x_{t+1} to NEXT x buffer ----
        if (t < Tt - 1) {
            half8 hx;
#pragma unroll
            for (int j = 0; j < 4; ++j) { hx[j] = (_Float16)pa[j]; hx[4 + j] = (_Float16)pb[j]; }
            int off = (srow * 256 + c8 * 2) ^ ((srow & 7) << 4);
            *(half8*)(smem + 8192 + (cur ^ 1) * 8192 + off) = hx;
        }
        __syncthreads();
        cur ^= 1;
    }

    // ---- epilogue: logits + softmax ----
#pragma unroll
    for (int mt = 0; mt < 2; ++mt)
#pragma unroll
        for (int i = 0; i < 4; ++i)
            outst[(mt * 16 + kg * 4 + i) * Ee + gc] = oreg[mt][i];
    __syncthreads();

    if (tid < 32 * Aa) {
        int r = tid / Aa, a = tid % Aa;
        const float* wo = w_out + a * Ee;
        const float* os = outst + r * Ee;
        float s = b_out[a];
#pragma unroll
        for (int j = 0; j < Ee; j += 4) {
            f32x4 o = *(const f32x4*)(os + j);
            f32x4 w4 = *(const f32x4*)(wo + j);
            s += o[0] * w4[0] + o[1] * w4[1] + o[2] * w4[2] + o[3] * w4[3];
        }
        lg[r * 12 + a] = s;
    }
    __syncthreads();
    if (tid < 32) {
        float v[Aa];
        float mx = -1e30f;
#pragma unroll
        for (int a = 0; a < Aa; ++a) {
            v[a] = lg[tid * 12 + a];
            mx = fmaxf(mx, v[a]);
        }
        float sum = 0.f;
#pragma unroll
        for (int a = 0; a < Aa; ++a) {
            v[a] = __expf(v[a] - mx);
            sum += v[a];
        }
        float inv = fast_rcp(sum);
#pragma unroll
        for (int a = 0; a < Aa; ++a) out[(size_t)(row0 + tid) * Aa + a] = v[a] * inv;
    }
}

extern "C" void kernel_launch(void* const* d_in, const int* in_sizes, int n_in,
                              void* d_out, int out_size, void* d_ws, size_t ws_size,
                              hipStream_t stream) {
    (void)in_sizes; (void)n_in; (void)d_ws; (void)ws_size; (void)out_size;
    const int* utt = (const int*)d_in[0];
    const float* emb = (const float*)d_in[2];
    const float* wih = (const float*)d_in[3];
    const float* whh = (const float*)d_in[4];
    const float* bih = (const float*)d_in[5];
    const float* bhh = (const float*)d_in[6];
    const float* wout = (const float*)d_in[7];
    const float* bout = (const float*)d_in[8];
    gru_fused_kernel<<<256, 512, 0, stream>>>(utt, emb, wih, whh, bih, bhh, wout, bout,
                                              (float*)d_out);
}

// Round 3
// 138.557 us; speedup vs baseline: 1.8530x; 1.4532x over previous
//
#include <hip/hip_runtime.h>
#include <hip/hip_fp16.h>

#define Tt 64
#define Ee 128
#define Aa 10

typedef __attribute__((ext_vector_type(8))) _Float16 half8;
typedef __attribute__((ext_vector_type(4))) float f32x4;

__device__ __forceinline__ float fast_rcp(float x) { return __builtin_amdgcn_rcpf(x); }

__device__ __forceinline__ half8 load_h8(const float* p) {
    f32x4 a = *(const f32x4*)p;
    f32x4 b = *(const f32x4*)(p + 4);
    half8 r;
    r[0] = (_Float16)a[0]; r[1] = (_Float16)a[1]; r[2] = (_Float16)a[2]; r[3] = (_Float16)a[3];
    r[4] = (_Float16)b[0]; r[5] = (_Float16)b[1]; r[6] = (_Float16)b[2]; r[7] = (_Float16)b[3];
    return r;
}

#define MFMA_F16(a, b, c)  __builtin_amdgcn_mfma_f32_16x16x32_f16(a, b, c, 0, 0, 0)

// LDS layout (bytes):
//   0      tokb   [32][64] int              8192
//   8192   X0     [32][128] f16 swizzled    8192   (epilogue: outst f32 aliases 8192..24576)
//   16384  X1                               8192
//   24576  H0     [32][128] f16 swizzled    8192
//   32768  H1                               8192
//   40960  lg     [32][12] f32              1536
//   42496  tstar  [32] int                   128
#define SM_BYTES 42624

// one WG = 32 rows, 8 waves; wave w owns hidden cols [16w,16w+16): its r-, z-, n- gate tiles.
__global__ __launch_bounds__(512, 2) void gru_fused_kernel(
    const int* __restrict__ utt, const float* __restrict__ emb,
    const float* __restrict__ w_ih, const float* __restrict__ w_hh,
    const float* __restrict__ b_ih, const float* __restrict__ b_hh,
    const float* __restrict__ w_out, const float* __restrict__ b_out,
    float* __restrict__ out) {
    __shared__ __align__(16) char smem[SM_BYTES];
    int* tokb = (int*)smem;
    float* lg = (float*)(smem + 40960);
    int* tstar = (int*)(smem + 42496);
    float* outst = (float*)(smem + 8192);

    const int tid = threadIdx.x;
    const int wv = tid >> 6;
    const int ln = tid & 63;
    const int fn = ln & 15;   // col-in-tile (B n-index / A m-row / C col)
    const int kg = ln >> 4;   // k-group
    const int row0 = blockIdx.x * 32;
    const int gc = wv * 16 + fn;  // hidden col owned by this lane
    const int srow = tid >> 4;          // staging row
    const int c8 = (tid & 15) << 3;     // staging col (8 floats)

    // ---- prologue: init tstar, zero H0 (h0 = 0 -> MFMAs exact) ----
    if (tid < 32) tstar[tid] = Tt - 1;
    *(f32x4*)(smem + 24576 + tid * 16) = (f32x4){0.f, 0.f, 0.f, 0.f};
    __syncthreads();
    // ---- stage all tokens + death-step scan ----
    {
        int4 tv = ((const int4*)(utt + (size_t)row0 * Tt))[tid];
        ((int4*)tokb)[tid] = tv;
        int row = tid >> 4;
        int tq = (tid & 15) << 2;
        if (tv.x == 0) atomicMin(&tstar[row], tq);
        if (tv.y == 0) atomicMin(&tstar[row], tq + 1);
        if (tv.z == 0) atomicMin(&tstar[row], tq + 2);
        if (tv.w == 0) atomicMin(&tstar[row], tq + 3);
    }

    // ---- weight fragments in registers (all f16) ----
    half8 wir[4], wiz[4], win[4], whr[4], whz[4], whn[4];
#pragma unroll
    for (int kt = 0; kt < 4; ++kt) {
        int k0 = kt * 32 + kg * 8;
        wir[kt] = load_h8(w_ih + (size_t)gc * Ee + k0);
        wiz[kt] = load_h8(w_ih + (size_t)(128 + gc) * Ee + k0);
        win[kt] = load_h8(w_ih + (size_t)(256 + gc) * Ee + k0);
        whr[kt] = load_h8(w_hh + (size_t)gc * Ee + k0);
        whz[kt] = load_h8(w_hh + (size_t)(128 + gc) * Ee + k0);
        whn[kt] = load_h8(w_hh + (size_t)(256 + gc) * Ee + k0);
    }
    const float bcr = b_ih[gc] + b_hh[gc];
    const float bcz = b_ih[128 + gc] + b_hh[128 + gc];
    const float bin = b_ih[256 + gc];
    const float bhn = b_hh[256 + gc];
    __syncthreads();

    // death steps for this lane's 8 rows
    int ts[8];
#pragma unroll
    for (int mt = 0; mt < 2; ++mt)
#pragma unroll
        for (int i = 0; i < 4; ++i) ts[mt * 4 + i] = tstar[mt * 16 + kg * 4 + i];

    // ---- stage x_0 ----
    {
        int tok = tokb[srow * Tt];
        const float* p = emb + (size_t)tok * Ee + c8;
        f32x4 a = *(const f32x4*)p;
        f32x4 b = *(const f32x4*)(p + 4);
        half8 hx;
#pragma unroll
        for (int j = 0; j < 4; ++j) { hx[j] = (_Float16)a[j]; hx[4 + j] = (_Float16)b[j]; }
        int off = (srow * 256 + c8 * 2) ^ ((srow & 7) << 4);
        *(half8*)(smem + 8192 + off) = hx;
    }
    __syncthreads();

    f32x4 hreg[2], oreg[2];
#pragma unroll
    for (int mt = 0; mt < 2; ++mt) {
        hreg[mt] = (f32x4){0.f, 0.f, 0.f, 0.f};
        oreg[mt] = (f32x4){0.f, 0.f, 0.f, 0.f};
    }

    int cur = 0;
#pragma unroll 1
    for (int t = 0; t < Tt; ++t) {
        // ---- issue prefetch of x_{t+1} (latency hides under MFMA phase) ----
        f32x4 pa, pb;
        if (t < Tt - 1) {
            int tok = tokb[srow * Tt + t + 1];
            const float* p = emb + (size_t)tok * Ee + c8;
            pa = *(const f32x4*)p;
            pb = *(const f32x4*)(p + 4);
        }

        const char* xb = smem + 8192 + cur * 8192;
        const char* hb = smem + 24576 + cur * 8192;

        // ---- MFMA: 6 products per (kt,mt), all f16 ----
        f32x4 ar[2], az[2], ain[2], ahn[2];
#pragma unroll
        for (int mt = 0; mt < 2; ++mt) {
            ar[mt] = (f32x4){0.f, 0.f, 0.f, 0.f};
            az[mt] = (f32x4){0.f, 0.f, 0.f, 0.f};
            ain[mt] = (f32x4){0.f, 0.f, 0.f, 0.f};
            ahn[mt] = (f32x4){0.f, 0.f, 0.f, 0.f};
        }
        __builtin_amdgcn_s_setprio(1);
#pragma unroll
        for (int kt = 0; kt < 4; ++kt) {
#pragma unroll
            for (int mt = 0; mt < 2; ++mt) {
                int r = mt * 16 + fn;
                int off = (r * 256 + (kt * 32 + kg * 8) * 2) ^ ((r & 7) << 4);
                half8 xa = *(const half8*)(xb + off);
                half8 ha = *(const half8*)(hb + off);
                ar[mt] = MFMA_F16(xa, wir[kt], ar[mt]);
                ar[mt] = MFMA_F16(ha, whr[kt], ar[mt]);
                az[mt] = MFMA_F16(xa, wiz[kt], az[mt]);
                az[mt] = MFMA_F16(ha, whz[kt], az[mt]);
                ain[mt] = MFMA_F16(xa, win[kt], ain[mt]);
                ahn[mt] = MFMA_F16(ha, whn[kt], ahn[mt]);
            }
        }
        __builtin_amdgcn_s_setprio(0);

        char* hn = smem + 24576 + (cur ^ 1) * 8192;

        // ---- gates + h update + snapshot (lane-local); write h_t to NEXT buffer ----
#pragma unroll
        for (int mt = 0; mt < 2; ++mt) {
#pragma unroll
            for (int i = 0; i < 4; ++i) {
                float pr = ar[mt][i] + bcr;
                float pz = az[mt][i] + bcz;
                float rr = fast_rcp(1.f + __expf(-pr));
                float zz = fast_rcp(1.f + __expf(-pz));
                float pn = ain[mt][i] + bin + rr * (ahn[mt][i] + bhn);
                float e2 = __expf(2.f * pn);
                float nn = 1.f - 2.f * fast_rcp(e2 + 1.f);  // tanh(pn)
                float h = (1.f - zz) * nn + zz * hreg[mt][i];
                hreg[mt][i] = h;
                if (t == ts[mt * 4 + i]) oreg[mt][i] = h;
                if (t < Tt - 1) {
                    int row = mt * 16 + kg * 4 + i;
                    int off = (row * 256 + gc * 2) ^ ((row & 7) << 4);
                    *(_Float16*)(hn + off) = (_Float16)h;
                }
            }
        }
        // ---- commit prefetched x_{t+1} to NEXT x buffer ----
        if (t < Tt - 1) {
            half8 hx;
#pragma unroll
            for (int j = 0; j < 4; ++j) { hx[j] = (_Float16)pa[j]; hx[4 + j] = (_Float16)pb[j]; }
            int off = (srow * 256 + c8 * 2) ^ ((srow & 7) << 4);
            *(half8*)(smem + 8192 + (cur ^ 1) * 8192 + off) = hx;
        }
        __syncthreads();
        cur ^= 1;
    }

    // ---- epilogue: logits + softmax ----
#pragma unroll
    for (int mt = 0; mt < 2; ++mt)
#pragma unroll
        for (int i = 0; i < 4; ++i)
            outst[(mt * 16 + kg * 4 + i) * Ee + gc] = oreg[mt][i];
    __syncthreads();

    if (tid < 32 * Aa) {
        int r = tid / Aa, a = tid % Aa;
        const float* wo = w_out + a * Ee;
        const float* os = outst + r * Ee;
        float s = b_out[a];
#pragma unroll
        for (int j = 0; j < Ee; j += 4) {
            f32x4 o = *(const f32x4*)(os + j);
            f32x4 w4 = *(const f32x4*)(wo + j);
            s += o[0] * w4[0] + o[1] * w4[1] + o[2] * w4[2] + o[3] * w4[3];
        }
        lg[r * 12 + a] = s;
    }
    __syncthreads();
    if (tid < 32) {
        float v[Aa];
        float mx = -1e30f;
#pragma unroll
        for (int a = 0; a < Aa; ++a) {
            v[a] = lg[tid * 12 + a];
            mx = fmaxf(mx, v[a]);
        }
        float sum = 0.f;
#pragma unroll
        for (int a = 0; a < Aa; ++a) {
            v[a] = __expf(v[a] - mx);
            sum += v[a];
        }
        float inv = fast_rcp(sum);
#pragma unroll
        for (int a = 0; a < Aa; ++a) out[(size_t)(row0 + tid) * Aa + a] = v[a] * inv;
    }
}

extern "C" void kernel_launch(void* const* d_in, const int* in_sizes, int n_in,
                              void* d_out, int out_size, void* d_ws, size_t ws_size,
                              hipStream_t stream) {
    (void)in_sizes; (void)n_in; (void)d_ws; (void)ws_size; (void)out_size;
    const int* utt = (const int*)d_in[0];
    const float* emb = (const float*)d_in[2];
    const float* wih = (const float*)d_in[3];
    const float* whh = (const float*)d_in[4];
    const float* bih = (const float*)d_in[5];
    const float* bhh = (const float*)d_in[6];
    const float* wout = (const float*)d_in[7];
    const float* bout = (const float*)d_in[8];
    gru_fused_kernel<<<256, 512, 0, stream>>>(utt, emb, wih, whh, bih, bhh, wout, bout,
                                              (float*)d_out);
}